// Round 1
// baseline (1675.470 us; speedup 1.0000x reference)
//
#include <hip/hip_runtime.h>

#define NB 64
#define NT 4096
#define NS 128
#define TILE 32
#define NTILES (NT / TILE)   // 128
#define NTH 512
#define GRP 40               // padded group stride: 32 floats + 8 pad -> banks 0/8/16/24

__global__ __launch_bounds__(NTH)
void crf_fwd(const float* __restrict__ obs,
             const float* __restrict__ trans,
             float* __restrict__ out)
{
    __shared__ float Pbuf[2][4 * GRP];   // P state, double-buffered, padded
    __shared__ float obsT[TILE * NS];    // 32-step obs tile (16 KB)
    __shared__ float wmax[NTH / 64];     // per-wave maxes for renorm

    const int tid = threadIdx.x;
    const int w   = tid >> 6;        // wave 0..7
    const int l   = tid & 63;        // lane
    const int j   = (w << 4) + (l >> 2);  // owned to-state 0..127
    const int sub = l & 3;           // i-slice 0..3 (32 rows each)

    // expA column slice -> registers (one-time, A is constant)
    float ea[32];
    {
        const float* tc = trans + j;
        #pragma unroll
        for (int k = 0; k < 32; ++k)
            ea[k] = __expf(tc[(sub * 32 + k) * NS]);
    }

    const float* obsB = obs + (size_t)blockIdx.x * NT * NS;

    // prefetch tile 0 into registers
    const float4* g0 = (const float4*)obsB;
    float4 r0 = g0[tid];
    float4 r1 = g0[tid + NTH];

    float L = 0.f;        // accumulated log-scale (identical in all threads)
    float rscale = 1.f;   // pending 1/M to apply at next window start

    for (int tile = 0; tile < NTILES; ++tile) {
        // stage current tile's obs (regs -> LDS), then prefetch next tile
        ((float4*)obsT)[tid]       = r0;
        ((float4*)obsT)[tid + NTH] = r1;
        if (tile + 1 < NTILES) {
            const float4* gn = (const float4*)(obsB + (size_t)(tile + 1) * TILE * NS);
            r0 = gn[tid];
            r1 = gn[tid + NTH];
        }
        __syncthreads();

        #pragma unroll 4
        for (int tt = 0; tt < TILE; ++tt) {
            const int t = tile * TILE + tt;
            float sp;
            if (t == 0) {
                sp = 1.f;  // P0[j] = exp(obs0[j])
            } else {
                // quarter-dot: s[j] partial over i in [32*sub, 32*sub+32)
                const float4* P4 = (const float4*)&Pbuf[(t + 1) & 1][sub * GRP];
                sp = 0.f;
                #pragma unroll
                for (int k = 0; k < 8; ++k) {
                    float4 p = P4[k];
                    sp = fmaf(p.x, ea[4 * k + 0], sp);
                    sp = fmaf(p.y, ea[4 * k + 1], sp);
                    sp = fmaf(p.z, ea[4 * k + 2], sp);
                    sp = fmaf(p.w, ea[4 * k + 3], sp);
                }
                // combine 4 sub-partials (same wave, lane bits 0..1)
                sp += __shfl_xor(sp, 1);
                sp += __shfl_xor(sp, 2);
            }
            if ((t & 3) == 0) sp *= rscale;      // lazy renorm apply
            const float o  = obsT[tt * NS + j];  // broadcast read
            const float Pn = sp * __expf(o);

            if ((t & 3) == 3) {
                // measure max over all 128 P' (all 4 lanes/group hold same Pn)
                float m = Pn;
                m = fmaxf(m, __shfl_xor(m, 4));
                m = fmaxf(m, __shfl_xor(m, 8));
                m = fmaxf(m, __shfl_xor(m, 16));
                m = fmaxf(m, __shfl_xor(m, 32));
                if (l == 0) wmax[w] = m;
            }
            if (sub == 0)
                Pbuf[t & 1][((j >> 5) * GRP) + (j & 31)] = Pn;
            __syncthreads();
            if ((t & 3) == 3 && t + 1 < NT) {
                float M = wmax[0];
                #pragma unroll
                for (int q = 1; q < NTH / 64; ++q) M = fmaxf(M, wmax[q]);
                rscale = 1.0f / M;
                L += __logf(M);
            }
        }
    }

    // epilogue: out[b] = -(log(sum_j P[j]) + L); final P is in Pbuf[1] (t=4095 odd)
    if (tid < 64) {
        const float* Pf = Pbuf[1];
        float a  = Pf[((tid >> 5) * GRP) + (tid & 31)];
        const int i2 = tid + 64;
        float b2 = Pf[((i2 >> 5) * GRP) + (i2 & 31)];
        float ssum = a + b2;
        ssum += __shfl_xor(ssum, 1);
        ssum += __shfl_xor(ssum, 2);
        ssum += __shfl_xor(ssum, 4);
        ssum += __shfl_xor(ssum, 8);
        ssum += __shfl_xor(ssum, 16);
        ssum += __shfl_xor(ssum, 32);
        if (tid == 0) out[blockIdx.x] = -(__logf(ssum) + L);
    }
}

extern "C" void kernel_launch(void* const* d_in, const int* in_sizes, int n_in,
                              void* d_out, int out_size, void* d_ws, size_t ws_size,
                              hipStream_t stream) {
    const float* obs   = (const float*)d_in[0];   // [64, 4096, 128] fp32
    const float* trans = (const float*)d_in[1];   // [128, 128] fp32
    float* out = (float*)d_out;                   // [64] fp32
    hipLaunchKernelGGL(crf_fwd, dim3(NB), dim3(NTH), 0, stream, obs, trans, out);
}